// Round 5
// baseline (580.292 us; speedup 1.0000x reference)
//
#include <hip/hip_runtime.h>
#include <stdint.h>

#define NN 64
#define PLN 4096          // plane: 64 rows x 64 shorts, 16B-block XOR swizzle, no pad

typedef __attribute__((ext_vector_type(8))) short short8;    // 8 bf16 = 4 VGPRs (K=16 operand)
typedef __attribute__((ext_vector_type(4))) float f32x4;
typedef __attribute__((ext_vector_type(16))) float f32x16;
typedef __attribute__((ext_vector_type(4))) unsigned int uint4v;

#define MFMA16(a, b, c) __builtin_amdgcn_mfma_f32_32x32x16_bf16((a), (b), (c), 0, 0, 0)

__device__ __forceinline__ float ubf(uint32_t u) {
    union { uint32_t i; float f; } v; v.i = u; return v.f;
}
// packed RNE f32->bf16 x2: dst[15:0]=bf16(lo arg), dst[31:16]=bf16(hi arg)
__device__ __forceinline__ uint32_t cvtpk_bf16(float lo, float hi) {
    uint32_t r;
    asm("v_cvt_pk_bf16_f32 %0, %1, %2" : "=v"(r) : "v"(lo), "v"(hi));
    return r;
}
// v_permlane32_swap_b32 a, b:  a' = {a.lo_half, b.lo_half}, b' = {a.hi_half, b.hi_half}
__device__ __forceinline__ void plswap(uint32_t& a, uint32_t& b) {
    asm("v_permlane32_swap_b32 %0, %1" : "+v"(a), "+v"(b));
}
__device__ __forceinline__ short8 u4s8(uint32_t a, uint32_t b, uint32_t c, uint32_t d) {
    union { uint4v u; short8 s; } t; t.u = (uint4v){a, b, c, d}; return t.s;
}

// Split strip (2 C-tiles, f32) into 16 hi + 16 lo packed words (for LDS store paths).
__device__ __forceinline__ void mk_words(const f32x16& s0, const f32x16& s1,
                                         uint32_t* wh, uint32_t* wl) {
#pragma unroll
    for (int q = 0; q < 2; ++q) {
        const f32x16& s = q ? s1 : s0;
#pragma unroll
        for (int j = 0; j < 8; ++j) {
            float v0 = s[2 * j], v1 = s[2 * j + 1];
            uint32_t h = cvtpk_bf16(v0, v1);
            float r0 = v0 - ubf(h << 16);
            float r1 = v1 - ubf(h & 0xFFFF0000u);
            wh[q * 8 + j] = h;
            wl[q * 8 + j] = cvtpk_bf16(r0, r1);
        }
    }
}
// words -> K=16 B-operand fragments via permlane32_swap
__device__ __forceinline__ void words_to_frags(const uint32_t* wh, const uint32_t* wl,
                                               short8* bh, short8* bl) {
#pragma unroll
    for (int q = 0; q < 2; ++q)
#pragma unroll
        for (int s2 = 0; s2 < 2; ++s2) {
            uint32_t a0 = wh[q * 8 + 4 * s2 + 0], b0 = wh[q * 8 + 4 * s2 + 2];
            uint32_t a1 = wh[q * 8 + 4 * s2 + 1], b1 = wh[q * 8 + 4 * s2 + 3];
            plswap(a0, b0); plswap(a1, b1);
            bh[2 * q + s2] = u4s8(a0, a1, b0, b1);
            uint32_t c0 = wl[q * 8 + 4 * s2 + 0], d0 = wl[q * 8 + 4 * s2 + 2];
            uint32_t c1 = wl[q * 8 + 4 * s2 + 1], d1 = wl[q * 8 + 4 * s2 + 3];
            plswap(c0, d0); plswap(c1, d1);
            bl[2 * q + s2] = u4s8(c0, c1, d0, d1);
        }
}
// Fused pack: strip f32 -> B-frags directly (no word arrays kept live)
__device__ __forceinline__ void pack_frags(const f32x16& s0, const f32x16& s1,
                                           short8* bh, short8* bl) {
#pragma unroll
    for (int q = 0; q < 2; ++q) {
        const f32x16& s = q ? s1 : s0;
#pragma unroll
        for (int s2 = 0; s2 < 2; ++s2) {
            uint32_t h[4], l[4];
#pragma unroll
            for (int p = 0; p < 4; ++p) {
                float v0 = s[8 * s2 + 2 * p], v1 = s[8 * s2 + 2 * p + 1];
                h[p] = cvtpk_bf16(v0, v1);
                float r0 = v0 - ubf(h[p] << 16);
                float r1 = v1 - ubf(h[p] & 0xFFFF0000u);
                l[p] = cvtpk_bf16(r0, r1);
            }
            plswap(h[0], h[2]); plswap(h[1], h[3]);
            bh[2 * q + s2] = u4s8(h[0], h[1], h[2], h[3]);
            plswap(l[0], l[2]); plswap(l[1], l[3]);
            bl[2 * q + s2] = u4s8(l[0], l[1], l[2], l[3]);
        }
    }
}
// Store own strip transposed (symmetry): plane row = own col cC
__device__ __forceinline__ void store_words(short* Ph, short* Pl,
                                            const uint32_t* wh, const uint32_t* wl,
                                            int cC, int lh, int l7) {
#pragma unroll
    for (int q = 0; q < 2; ++q)
#pragma unroll
        for (int g = 0; g < 4; ++g) {
            int idx = cC * 64 + ((((4 * q + g) ^ l7)) << 3) + 4 * lh;
            uint2 vh; vh.x = wh[q * 8 + g * 2]; vh.y = wh[q * 8 + g * 2 + 1];
            *(uint2*)(Ph + idx) = vh;
            uint2 vl; vl.x = wl[q * 8 + g * 2]; vl.y = wl[q * 8 + g * 2 + 1];
            *(uint2*)(Pl + idx) = vl;
        }
}
// c0/c1 += A * strip, split precision (ah*bh + ah*bl + al*bh), K=64 over 4 chunks.
__device__ __forceinline__ void mm24(const short8 (&ah)[2][4], const short8 (&al)[2][4],
                                     const short8* bh, const short8* bl,
                                     f32x16& c0, f32x16& c1) {
#pragma unroll
    for (int kk = 0; kk < 4; ++kk) {
        c0 = MFMA16(ah[0][kk], bh[kk], c0);
        c1 = MFMA16(ah[1][kk], bh[kk], c1);
        c0 = MFMA16(ah[0][kk], bl[kk], c0);
        c1 = MFMA16(ah[1][kk], bl[kk], c1);
        c0 = MFMA16(al[0][kk], bh[kk], c0);
        c1 = MFMA16(al[1][kk], bh[kk], c1);
    }
}

__global__ __launch_bounds__(128, 2)
void spdlogexp(const float* __restrict__ fin,
               const float* __restrict__ win,
               float* __restrict__ outp) {
    __shared__ __align__(16) short lds[4 * PLN];   // 32 KB: X plane (2T), S plane (2S)
    __shared__ __align__(16) float wsh[NN];
    __shared__ float ecoef[16];    // even-part Chebyshev coeffs in s (deg 15)
    __shared__ float qcoef[15];    // odd-part-derived coeffs in s (deg 14)

    const int tid = threadIdx.x;
    const int blk = blockIdx.x;
    const int lane = tid & 63;
    const int wv = tid >> 6;          // wave = column strip [32wv, 32wv+32)
    const int lh = lane >> 5;
    const int l31 = lane & 31;
    const int l7 = lane & 7;
    const int cC = 32 * wv + l31;     // own column

    short* Xh = lds;
    short* Xl = lds + PLN;
    short* Sh = lds + 2 * PLN;
    short* Sl = lds + 3 * PLN;

    const float aLo = 0.09f, aHi = 6.3f;
    const float mC = 0.5f * (aLo + aHi), rC = 0.5f * (aHi - aLo);
    const float invR2 = 2.0f / rC;    // store 2T

    // ---- Phase 0: load X, 2T = 2(X - mC I)/rC -> hi/lo bf16 into X plane ----
    {
        const float4* src = (const float4*)(fin + (size_t)blk * (NN * NN));
#pragma unroll
        for (int c = 0; c < 8; ++c) {
            int v4 = c * 128 + tid;
            float4 v = src[v4];
            int e0 = v4 << 2;
            int i = e0 >> 6, j = e0 & 63;
            float t0 = (v.x - ((j + 0 == i) ? mC : 0.0f)) * invR2;
            float t1 = (v.y - ((j + 1 == i) ? mC : 0.0f)) * invR2;
            float t2 = (v.z - ((j + 2 == i) ? mC : 0.0f)) * invR2;
            float t3 = (v.w - ((j + 3 == i) ? mC : 0.0f)) * invR2;
            uint32_t h01 = cvtpk_bf16(t0, t1);
            uint32_t h23 = cvtpk_bf16(t2, t3);
            float r0 = t0 - ubf(h01 << 16);
            float r1 = t1 - ubf(h01 & 0xFFFF0000u);
            float r2 = t2 - ubf(h23 << 16);
            float r3 = t3 - ubf(h23 & 0xFFFF0000u);
            int idx = i * 64 + ((((j >> 3) ^ (i & 7)) << 3) | (j & 7));
            uint2 ph; ph.x = h01; ph.y = h23;
            uint2 pl; pl.x = cvtpk_bf16(r0, r1); pl.y = cvtpk_bf16(r2, r3);
            *(uint2*)(Xh + idx) = ph;
            *(uint2*)(Xl + idx) = pl;
        }
    }
    if (tid < NN) wsh[tid] = win[(size_t)blk * NN + tid];
    if (tid < 31) {
        // log on [aLo,aHi]: c_k = -2 u^k / k, u = -(mr - sqrt(mr^2-1)), a = |u|.
        // Even: sum c_{2m} T_{2m}(t) = sum e_m T_m(s), s = 2t^2-1, e_m = c_{2m}.
        // Odd:  sum c_{2m+1} T_{2m+1}(t) = t * sum q_j T_j(s),
        //       q_j = (j? 2:1) * sum_{m>=j} (-1)^{m-j} c_{2m+1},  c_{2m+1} = +2 a^{2m+1}/(2m+1)
        float mr = mC / rC;
        float a = mr - sqrtf(mr * mr - 1.0f);
        if (tid < 16) {
            if (tid == 0) ecoef[0] = logf(rC / (2.0f * a));
            else ecoef[tid] = -2.0f * powf(a, 2.0f * (float)tid) / (2.0f * (float)tid);
        } else {
            int j = tid - 16;
            float p = powf(a, (float)(2 * j + 1));
            float s = 0.0f, sg = 1.0f;
            for (int m = j; m <= 14; ++m) {
                s += sg * 2.0f * p / (float)(2 * m + 1);
                p *= a * a; sg = -sg;
            }
            qcoef[j] = (j == 0) ? s : 2.0f * s;
        }
    }
    __syncthreads();

    // ---- A-fragment loader: frag(q,kk) = M[32q+l31, 16kk+8lh+{0..7}] (swizzled) ----
    short8 th[2][4], tl[2][4];
    auto loadfrags = [&](const short* Ph, const short* Pl) {
#pragma unroll
        for (int q = 0; q < 2; ++q)
#pragma unroll
            for (int kk = 0; kk < 4; ++kk) {
                int idx = (32 * q + l31) * 64 + (((2 * kk + lh) ^ l7) << 3);
                th[q][kk] = *(const short8*)(Ph + idx);
                tl[q][kk] = *(const short8*)(Pl + idx);
            }
    };

    // ---- diag mask + strip selectors ----
    float dm[16];
#pragma unroll
    for (int i = 0; i < 16; ++i) {
        int rp = 8 * (i >> 2) + 4 * lh + (i & 3);
        dm[i] = (rp == l31) ? 1.0f : 0.0f;
    }
    const float ds0 = (wv == 0) ? 1.0f : 0.0f;
    const float ds1 = 1.0f - ds0;

    // ---- Build 2S = (2T)(2T) - 2I, store to S plane ----
    loadfrags(Xh, Xl);   // 2T A-frags
    {
        short8 sbh[4], sbl[4];   // B-frags of 2T at own column (row cC by symmetry)
#pragma unroll
        for (int kk = 0; kk < 4; ++kk) {
            int idx = cC * 64 + (((2 * kk + lh) ^ l7) << 3);
            sbh[kk] = *(const short8*)(Xh + idx);
            sbl[kk] = *(const short8*)(Xl + idx);
        }
        f32x16 s20, s21;
#pragma unroll
        for (int i = 0; i < 16; ++i) { s20[i] = -2.0f * dm[i] * ds0; s21[i] = -2.0f * dm[i] * ds1; }
        mm24(th, tl, sbh, sbl, s20, s21);
        uint32_t wwh[16], wwl[16];
        mk_words(s20, s21, wwh, wwl);
        store_words(Sh, Sl, wwh, wwl, cC, lh, l7);
    }
    __syncthreads();
    loadfrags(Sh, Sl);   // th/tl <- 2S frags for both chains

    // ---- Two independent Clenshaw chains in S (even deg 15, odd deg 14) ----
    f32x16 EA0, EA1, EB0, EB1, OA0, OA1, OB0, OB1;
    {
        const float e15 = ecoef[15], q14 = qcoef[14];
#pragma unroll
        for (int i = 0; i < 16; ++i) {
            EA0[i] = 0.0f; EA1[i] = 0.0f;
            OA0[i] = 0.0f; OA1[i] = 0.0f;
            EB0[i] = e15 * dm[i] * ds0; EB1[i] = e15 * dm[i] * ds1;
            OB0[i] = q14 * dm[i] * ds0; OB1[i] = q14 * dm[i] * ds1;
        }
    }
    // dst := fac*(ck I - dst) + (2S)*pack(src)
    auto cstep = [&](f32x16& d0, f32x16& d1, const f32x16& s0, const f32x16& s1,
                     float ck, float fac) {
        short8 bh[4], bl[4];
        pack_frags(s0, s1, bh, bl);
        const float c0v = ck * ds0, c1v = ck * ds1;
#pragma unroll
        for (int i = 0; i < 16; ++i) {
            d0[i] = fac * fmaf(c0v, dm[i], -d0[i]);
            d1[i] = fac * fmaf(c1v, dm[i], -d1[i]);
        }
        mm24(th, tl, bh, bl, d0, d1);
    };
    // slot schedule: E(14)&O(13); pairs down to E(2)&O(1); E(1)&O-final; E-final.
    cstep(EA0, EA1, EB0, EB1, ecoef[14], 1.0f);
    cstep(OA0, OA1, OB0, OB1, qcoef[13], 1.0f);
#pragma unroll 1
    for (int m = 13; m >= 3; m -= 2) {
        cstep(EB0, EB1, EA0, EA1, ecoef[m], 1.0f);
        cstep(OB0, OB1, OA0, OA1, qcoef[m - 1], 1.0f);
        cstep(EA0, EA1, EB0, EB1, ecoef[m - 1], 1.0f);
        cstep(OA0, OA1, OB0, OB1, qcoef[m - 2], 1.0f);
    }
    cstep(EB0, EB1, EA0, EA1, ecoef[1], 1.0f);   // E(1): b1 -> EB, b2 in EA
    cstep(OB0, OB1, OA0, OA1, qcoef[0], 2.0f);   // O-final: OB = 2q
    cstep(EA0, EA1, EB0, EB1, ecoef[0], 2.0f);   // E-final: EA = 2p

    // ---- Combine: 4L = 2*(2p) + (2T)*(2q);  A = w_i w_j L / 16 ----
    loadfrags(Xh, Xl);   // th/tl <- 2T again (X untouched since phase 0)
    f32x16 aF0, aF1;
    {
        short8 bh[4], bl[4];
        pack_frags(OB0, OB1, bh, bl);
        f32x16 c0, c1;
#pragma unroll
        for (int i = 0; i < 16; ++i) { c0[i] = 2.0f * EA0[i]; c1[i] = 2.0f * EA1[i]; }
        mm24(th, tl, bh, bl, c0, c1);
        const float wc = wsh[cC] * 0.015625f;   // 1/64: 4L -> L and /16 scaling
#pragma unroll
        for (int g = 0; g < 4; ++g) {
            f32x4 w40 = *(const f32x4*)(wsh + 8 * g + 4 * lh);
            f32x4 w41 = *(const f32x4*)(wsh + 32 + 8 * g + 4 * lh);
#pragma unroll
            for (int r = 0; r < 4; ++r) {
                aF0[4 * g + r] = w40[r] * wc * c0[4 * g + r];
                aF1[4 * g + r] = w41[r] * wc * c1[4 * g + r];
            }
        }
    }
    __syncthreads();   // partner done reloading 2T frags; X plane writable

    uint32_t wwh[16], wwl[16];
    short8 pb[4], plo[4];
    // ---- store A -> X; M2 = A*A ----
    mk_words(aF0, aF1, wwh, wwl);
    store_words(Xh, Xl, wwh, wwl, cC, lh, l7);
    words_to_frags(wwh, wwl, pb, plo);
    __syncthreads();
    loadfrags(Xh, Xl);                 // A-frags
    f32x16 m20, m21;
#pragma unroll
    for (int i = 0; i < 16; ++i) { m20[i] = 0.0f; m21[i] = 0.0f; }
    mm24(th, tl, pb, plo, m20, m21);
    // ---- M3 = A*M2 ----
    mk_words(m20, m21, wwh, wwl);
    words_to_frags(wwh, wwl, pb, plo);
    f32x16 m30, m31;
#pragma unroll
    for (int i = 0; i < 16; ++i) { m30[i] = 0.0f; m31[i] = 0.0f; }
    mm24(th, tl, pb, plo, m30, m31);
    // ---- b0 = I + A + M2/2 ; G = I/6 + A/24 + M2/120 + M3/720 ----
    f32x16 b00, b01, g0, g1;
#pragma unroll
    for (int i = 0; i < 16; ++i) {
        float d0 = dm[i] * ds0, d1 = dm[i] * ds1;
        b00[i] = d0 + aF0[i] + 0.5f * m20[i];
        b01[i] = d1 + aF1[i] + 0.5f * m21[i];
        g0[i] = (1.0f / 6.0f) * d0 + (1.0f / 24.0f) * aF0[i] +
                (1.0f / 120.0f) * m20[i] + (1.0f / 720.0f) * m30[i];
        g1[i] = (1.0f / 6.0f) * d1 + (1.0f / 24.0f) * aF1[i] +
                (1.0f / 120.0f) * m21[i] + (1.0f / 720.0f) * m31[i];
    }
    __syncthreads();   // partner done loading A-frags; X writable
    // ---- store G -> X; P = b0 + G*M3 ----
    mk_words(g0, g1, wwh, wwl);
    store_words(Xh, Xl, wwh, wwl, cC, lh, l7);
    mk_words(m30, m31, wwh, wwl);
    words_to_frags(wwh, wwl, pb, plo);   // B = M3
    __syncthreads();
    loadfrags(Xh, Xl);                   // G-frags
    mm24(th, tl, pb, plo, b00, b01);     // P = b0 + G*M3

    // ---- 4 squarings, double-buffered (S, X, S, X): exp(M) = P^16 ----
#pragma unroll 1
    for (int it = 0; it < 4; ++it) {
        short* Dh = (it & 1) ? Xh : Sh;
        short* Dl = (it & 1) ? Xl : Sl;
        mk_words(b00, b01, wwh, wwl);
        store_words(Dh, Dl, wwh, wwl, cC, lh, l7);
        words_to_frags(wwh, wwl, pb, plo);
        __syncthreads();
        loadfrags(Dh, Dl);
        f32x16 n0, n1;
#pragma unroll
        for (int i = 0; i < 16; ++i) { n0[i] = 0.0f; n1[i] = 0.0f; }
        mm24(th, tl, pb, plo, n0, n1);
        b00 = n0; b01 = n1;
    }

    // ---- stage transposed f32 over X region (16 KB), swizzled ----
    __syncthreads();                     // partner done with final frag loads
    {
        float* stg = (float*)lds;
#pragma unroll
        for (int q = 0; q < 2; ++q)
#pragma unroll
            for (int g = 0; g < 4; ++g) {
                const f32x16& srcv = q ? b01 : b00;
                f32x4 v;
#pragma unroll
                for (int r = 0; r < 4; ++r) v[r] = srcv[4 * g + r];
                int bblk = 8 * q + 2 * g + lh;
                *(f32x4*)(stg + cC * 64 + ((bblk ^ l7) << 2)) = v;
            }
    }
    __syncthreads();

    // ---- coalesced float4 store (out = C^T = C by symmetry) ----
    {
        const float* stg = (const float*)lds;
        float4* dst = (float4*)(outp + (size_t)blk * (NN * NN));
#pragma unroll
        for (int c = 0; c < 8; ++c) {
            int v4 = c * 128 + tid;
            int i = v4 >> 4, jb = v4 & 15;
            f32x4 v = *(const f32x4*)(stg + i * 64 + ((jb ^ (i & 7)) << 2));
            float4 o; o.x = v[0]; o.y = v[1]; o.z = v[2]; o.w = v[3];
            dst[v4] = o;
        }
    }
}

extern "C" void kernel_launch(void* const* d_in, const int* in_sizes, int n_in,
                              void* d_out, int out_size, void* d_ws, size_t ws_size,
                              hipStream_t stream) {
    const float* f = (const float*)d_in[0];
    const float* w = (const float*)d_in[1];
    float* o = (float*)d_out;
    int B = in_sizes[0] / (NN * NN);
    spdlogexp<<<dim3(B), dim3(128), 0, stream>>>(f, w, o);
}